// Round 1
// baseline (1175.585 us; speedup 1.0000x reference)
//
#include <hip/hip_runtime.h>
#include <hip/hip_fp16.h>

// ---------------------------------------------------------------------------
// LSTMBijection: embed -> 6x LSTM (MFMA f16, weights register-resident,
// layer-pipelined via 11 persistent WGs + device-scope flags) -> LN -> head.
// ---------------------------------------------------------------------------

typedef _Float16 f16;
typedef _Float16 f16x4 __attribute__((ext_vector_type(4)));
typedef _Float16 f16x8 __attribute__((ext_vector_type(8)));
typedef float    f32x4 __attribute__((ext_vector_type(4)));

#define DEV static __device__ __forceinline__

constexpr int Tn   = 128;           // sequence length
constexpr int Bn   = 32;            // batch
constexpr int Dn   = 192;           // hidden dim
constexpr int H4n  = 768;           // 4*D
constexpr int Vn   = 32000;         // vocab
constexpr int Ln   = 6;             // layers
constexpr int LDSS = 200;           // padded LDS row stride (f16) -> 400B rows, 16B aligned, 2-way banks (free)
constexpr int GXT  = 96 * 64 * 4;   // 24576 f16 per timestep of gx (swizzled frag layout)

DEV f32x4 mfma16(f16x8 a, f16x8 b, f32x4 c) {
    return __builtin_amdgcn_mfma_f32_16x16x32_f16(a, b, c, 0, 0, 0);
}

DEV float fast_rcp(float x) { return __builtin_amdgcn_rcpf(x); }
DEV float sigm(float x)  { return fast_rcp(1.f + __expf(-x)); }
DEV float tanh_(float x) { float e = __expf(-2.f * x); return (1.f - e) * fast_rcp(1.f + e); }

DEV void spin_wait(const int* p, long& budget) {
    while (budget > 0) {
        if (__hip_atomic_load(p, __ATOMIC_ACQUIRE, __HIP_MEMORY_SCOPE_AGENT) != 0) return;
        --budget;
        __builtin_amdgcn_s_sleep(2);
    }
}

// Load B-fragments of a [768,192] f16 weight matrix for this wave.
// Wave w owns gate-columns {16w..16w+15} of each of the 4 gates:
// N-tile (g) covers rows 192*g + 16*wave + [0,16).  B-frag: n = lane&15, k = (lane>>4)*8 + j.
DEV void load_wfrags(const f16* __restrict__ wbase, f16x8 (&wf)[4][6], int wave, int lane) {
    const int quad = lane >> 4, n16 = lane & 15;
#pragma unroll
    for (int g = 0; g < 4; ++g)
#pragma unroll
        for (int kk = 0; kk < 6; ++kk) {
            const int row = g * Dn + wave * 16 + n16;
            wf[g][kk] = *(const f16x8*)(wbase + (size_t)row * Dn + kk * 32 + quad * 8);
        }
}

// One gx timestep: stage x_t [32][192] f16 -> LDS, MFMA vs resident W_ih frags,
// store gates pre-swizzled in C-frag lane order (8B per lane per (g,mt)).
DEV void gx_body(const f16* __restrict__ xt, f16* __restrict__ gxt,
                 const f16x8 (&wf)[4][6], const float (&bias4)[4],
                 f16* __restrict__ lds, int tid) {
    const int wave = tid >> 6, lane = tid & 63, quad = lane >> 4, n16 = lane & 15;
    {   // stage: 768 threads x 16B = 12288B = full [32][192] f16 tile
        const int row = tid / 24, col = (tid % 24) * 8;
        *(f16x8*)(&lds[row * LDSS + col]) = *(const f16x8*)(xt + row * Dn + col);
    }
    __syncthreads();
    f32x4 acc[4][2];
#pragma unroll
    for (int g = 0; g < 4; ++g) {
        const f32x4 bv = {bias4[g], bias4[g], bias4[g], bias4[g]};
        acc[g][0] = bv; acc[g][1] = bv;
    }
#pragma unroll
    for (int kk = 0; kk < 6; ++kk) {
        const f16x8 a0 = *(const f16x8*)(&lds[(n16     ) * LDSS + kk * 32 + quad * 8]);
        const f16x8 a1 = *(const f16x8*)(&lds[(n16 + 16) * LDSS + kk * 32 + quad * 8]);
#pragma unroll
        for (int g = 0; g < 4; ++g) {
            acc[g][0] = mfma16(a0, wf[g][kk], acc[g][0]);
            acc[g][1] = mfma16(a1, wf[g][kk], acc[g][1]);
        }
    }
#pragma unroll
    for (int g = 0; g < 4; ++g)
#pragma unroll
        for (int mt = 0; mt < 2; ++mt) {
            const f16x4 v = {(f16)acc[g][mt][0], (f16)acc[g][mt][1],
                             (f16)acc[g][mt][2], (f16)acc[g][mt][3]};
            *(f16x4*)(gxt + (size_t)(((wave * 4 + g) * 2 + mt) * 64 + lane) * 4) = v;
        }
}

// ------------------------------- kernels -----------------------------------

__global__ __launch_bounds__(256) void k_prep(
    const float* __restrict__ Wih, const float* __restrict__ Whh,
    const float* __restrict__ bih, const float* __restrict__ bhh,
    const float* __restrict__ emb,
    f16* __restrict__ wih16, f16* __restrict__ whh16,
    float* __restrict__ bias, f16* __restrict__ emb16, int* __restrict__ flags) {
    const long tid = (long)blockIdx.x * blockDim.x + threadIdx.x;
    const long stride = (long)gridDim.x * blockDim.x;
    const long nW = (long)Ln * H4n * Dn;                 // 884736
    for (long i = tid; i < nW; i += stride) { wih16[i] = (f16)Wih[i]; whh16[i] = (f16)Whh[i]; }
    const long nE = (long)Vn * Dn;                       // 6.144M
    for (long i = tid; i < nE; i += stride) emb16[i] = (f16)emb[i];
    for (long i = tid; i < Ln * H4n; i += stride) bias[i] = bih[i] + bhh[i];
    for (long i = tid; i < 2 * Ln * Tn; i += stride) flags[i] = 0;
}

__global__ __launch_bounds__(256) void k_embed(
    const int* __restrict__ x, const float* __restrict__ tok, const float* __restrict__ pos,
    f16* __restrict__ seq0) {
    const int r = blockIdx.x * 4 + (threadIdx.x >> 6);   // r = t*32 + b  (t-major)
    const int lane = threadIdx.x & 63;
    const int t = r >> 5, b = r & 31;
    const int idx = x[b * Tn + t];
    for (int j = lane; j < Dn; j += 64)
        seq0[(size_t)r * Dn + j] = (f16)(tok[(size_t)idx * Dn + j] + pos[t * Dn + j]);
}

// layer-0 input projection for all t (parallel, W_ih[0] register-resident)
__global__ __launch_bounds__(768, 3) void k_gx0(
    const f16* __restrict__ wih16, const float* __restrict__ bias,
    const f16* __restrict__ seq0, f16* __restrict__ gx0) {
    __shared__ f16 lds[Bn * LDSS];
    const int tid = threadIdx.x, wave = tid >> 6, lane = tid & 63, n16 = lane & 15;
    f16x8 wf[4][6];
    load_wfrags(wih16, wf, wave, lane);
    float bias4[4];
#pragma unroll
    for (int g = 0; g < 4; ++g) bias4[g] = bias[g * Dn + wave * 16 + n16];
    for (int tt = 0; tt < 4; ++tt) {
        const int t = tt * 32 + blockIdx.x;              // 32 blocks x 4 t
        gx_body(seq0 + (size_t)t * Bn * Dn, gx0 + (size_t)t * GXT, wf, bias4, lds, tid);
        __syncthreads();
    }
}

// 11 persistent WGs: bid 0..5 = recurrence for layer bid; bid 6..10 = gx producer for layer bid-5.
__global__ __launch_bounds__(768, 3) void k_pipeline(
    const f16* __restrict__ wih16, const f16* __restrict__ whh16, const float* __restrict__ bias,
    f16* __restrict__ seqbufs,   // [7][4096][192] f16; seq[0]=embed, seq[l+1]=layer l out
    f16* __restrict__ gxbufs,    // [6][128][GXT]
    int* __restrict__ hready,    // [6][128]
    int* __restrict__ gxready) { // [6][128] (row 0 unused)
    __shared__ f16 lds[Bn * LDSS];
    const int bid = blockIdx.x, tid = threadIdx.x;
    const int wave = tid >> 6, lane = tid & 63, quad = lane >> 4, n16 = lane & 15;
    long budget = 30000000;

    if (bid < 6) {
        // ================= recurrence, layer l =================
        const int l = bid;
        f16x8 wf[4][6];
        load_wfrags(whh16 + (size_t)l * H4n * Dn, wf, wave, lane);
        for (int i = tid; i < Bn * LDSS; i += 768) lds[i] = (f16)0.f;
        float c[2][4] = {{0.f, 0.f, 0.f, 0.f}, {0.f, 0.f, 0.f, 0.f}};
        f16* hout = seqbufs + (size_t)(l + 1) * Tn * Bn * Dn;
        const f16* gxl = gxbufs + (size_t)l * Tn * GXT;
        const int* gfl = gxready + l * Tn;
        int* hfl = hready + l * Tn;
        const int d = wave * 16 + n16;
        __syncthreads();
        for (int t = 0; t < Tn; ++t) {
            if (l > 0 && tid == 0) spin_wait(&gfl[t], budget);
            __syncthreads();                             // B1: gx_t visible; prev writes done
            const f16* gxt = gxl + (size_t)t * GXT;
            f32x4 acc[4][2];
#pragma unroll
            for (int g = 0; g < 4; ++g)
#pragma unroll
                for (int mt = 0; mt < 2; ++mt) {
                    const f16x4 v = *(const f16x4*)(gxt + (size_t)(((wave * 4 + g) * 2 + mt) * 64 + lane) * 4);
                    acc[g][mt] = (f32x4){(float)v[0], (float)v[1], (float)v[2], (float)v[3]};
                }
#pragma unroll
            for (int kk = 0; kk < 6; ++kk) {
                const f16x8 a0 = *(const f16x8*)(&lds[(n16     ) * LDSS + kk * 32 + quad * 8]);
                const f16x8 a1 = *(const f16x8*)(&lds[(n16 + 16) * LDSS + kk * 32 + quad * 8]);
#pragma unroll
                for (int g = 0; g < 4; ++g) {
                    acc[g][0] = mfma16(a0, wf[g][kk], acc[g][0]);
                    acc[g][1] = mfma16(a1, wf[g][kk], acc[g][1]);
                }
            }
            __syncthreads();                             // B2: all reads of h_{t-1} done
#pragma unroll
            for (int mt = 0; mt < 2; ++mt)
#pragma unroll
                for (int r = 0; r < 4; ++r) {
                    const float gi = sigm (acc[0][mt][r]);
                    const float gf = sigm (acc[1][mt][r]);
                    const float gg = tanh_(acc[2][mt][r]);
                    const float go = sigm (acc[3][mt][r]);
                    const float cn = gf * c[mt][r] + gi * gg;
                    c[mt][r] = cn;
                    const f16 hn = (f16)(go * tanh_(cn));
                    const int b = mt * 16 + quad * 4 + r;
                    lds[b * LDSS + d] = hn;
                    hout[((size_t)t * Bn + b) * Dn + d] = hn;
                }
            __syncthreads();                             // B3: h_t stores drained (vmcnt0 at barrier)
            if (tid == 0)
                __hip_atomic_store(&hfl[t], 1, __ATOMIC_RELEASE, __HIP_MEMORY_SCOPE_AGENT);
        }
    } else {
        // ================= gx producer, layer l = bid-5 (1..5) =================
        const int l = bid - 5;
        f16x8 wf[4][6];
        load_wfrags(wih16 + (size_t)l * H4n * Dn, wf, wave, lane);
        float bias4[4];
#pragma unroll
        for (int g = 0; g < 4; ++g) bias4[g] = bias[l * H4n + g * Dn + wave * 16 + n16];
        const f16* xin = seqbufs + (size_t)l * Tn * Bn * Dn;  // seq[l] = layer l-1 output
        f16* gxl = gxbufs + (size_t)l * Tn * GXT;
        const int* hfl = hready + (l - 1) * Tn;
        int* gfl = gxready + l * Tn;
        for (int t = 0; t < Tn; ++t) {
            if (tid == 0) spin_wait(&hfl[t], budget);
            __syncthreads();                             // x_t visible; lds reusable
            gx_body(xin + (size_t)t * Bn * Dn, gxl + (size_t)t * GXT, wf, bias4, lds, tid);
            __syncthreads();                             // gx stores drained
            if (tid == 0)
                __hip_atomic_store(&gfl[t], 1, __ATOMIC_RELEASE, __HIP_MEMORY_SCOPE_AGENT);
        }
    }
}

__global__ __launch_bounds__(256) void k_ln(
    const f16* __restrict__ h5, const float* __restrict__ gamma, const float* __restrict__ beta,
    float* __restrict__ outh, f16* __restrict__ hln) {
    const int r = blockIdx.x * 4 + (threadIdx.x >> 6);   // r = t*32 + b
    const int lane = threadIdx.x & 63;
    const f16* row = h5 + (size_t)r * Dn;
    const float v0 = (float)row[lane], v1 = (float)row[lane + 64], v2 = (float)row[lane + 128];
    float s = v0 + v1 + v2, sq = v0 * v0 + v1 * v1 + v2 * v2;
#pragma unroll
    for (int off = 1; off < 64; off <<= 1) { s += __shfl_xor(s, off); sq += __shfl_xor(sq, off); }
    const float mu = s * (1.f / Dn);
    const float var = sq * (1.f / Dn) - mu * mu;
    const float rs = rsqrtf(var + 1e-5f);
    const int t = r >> 5, b = r & 31;
    float* orow = outh + ((size_t)b * Tn + t) * Dn;
    f16* hrow = hln + (size_t)r * Dn;
    const float vv[3] = {v0, v1, v2};
#pragma unroll
    for (int k = 0; k < 3; ++k) {
        const int j = lane + 64 * k;
        const float y = (vv[k] - mu) * rs * gamma[j] + beta[j];
        orow[j] = y;
        hrow[j] = (f16)y;
    }
}

// Head: logits[b,t,v] = h_ln[m] . emb16[v], M=4096 K=192 N=32000.
// Mblk=64, Nblk=256 (8 waves x 2 N-tiles). XCD-swizzled nblk for L2-resident emb slices.
__global__ __launch_bounds__(512, 2) void k_head(
    const f16* __restrict__ hln, const f16* __restrict__ emb16, float* __restrict__ outl) {
    const int bid = blockIdx.x;
    const int nblk = (bid & 7) * 16 + ((bid >> 3) & 15); // 0..127, XCD = bid%8 owns 16 nblks
    const int mblk = bid >> 7;                           // 0..63
    if (nblk >= 125) return;                             // 125*256 = 32000 exactly
    __shared__ f16 alds[64 * LDSS];
    const int tid = threadIdx.x, wave = tid >> 6, lane = tid & 63, quad = lane >> 4, n16 = lane & 15;
    const f16* asrc = hln + (size_t)mblk * 64 * Dn;
#pragma unroll
    for (int j = 0; j < 3; ++j) {                        // 1536 groups of 8 f16
        const int g8 = tid + j * 512;
        const int row = g8 / 24, col = (g8 % 24) * 8;
        *(f16x8*)(&alds[row * LDSS + col]) = *(const f16x8*)(asrc + row * Dn + col);
    }
    __syncthreads();
    const int v00 = (nblk * 16 + wave * 2) * 16;
    const f16* b0p = emb16 + (size_t)(v00 + n16) * Dn + quad * 8;
    const f16* b1p = b0p + (size_t)16 * Dn;
    f32x4 acc[4][2];
#pragma unroll
    for (int mt = 0; mt < 4; ++mt) { acc[mt][0] = (f32x4){0.f,0.f,0.f,0.f}; acc[mt][1] = (f32x4){0.f,0.f,0.f,0.f}; }
#pragma unroll
    for (int kk = 0; kk < 6; ++kk) {
        const f16x8 b0 = *(const f16x8*)(b0p + kk * 32);
        const f16x8 b1 = *(const f16x8*)(b1p + kk * 32);
#pragma unroll
        for (int mt = 0; mt < 4; ++mt) {
            const f16x8 a = *(const f16x8*)(&alds[(mt * 16 + n16) * LDSS + kk * 32 + quad * 8]);
            acc[mt][0] = mfma16(a, b0, acc[mt][0]);
            acc[mt][1] = mfma16(a, b1, acc[mt][1]);
        }
    }
#pragma unroll
    for (int mt = 0; mt < 4; ++mt)
#pragma unroll
        for (int nt = 0; nt < 2; ++nt) {
            const int v0 = v00 + nt * 16;
#pragma unroll
            for (int r = 0; r < 4; ++r) {
                const int m = mblk * 64 + mt * 16 + quad * 4 + r;
                const int t = m >> 5, b = m & 31;
                __builtin_nontemporal_store(acc[mt][nt][r],
                    outl + ((size_t)b * Tn + t) * (size_t)Vn + v0 + n16);
            }
        }
}

// ------------------------------ launcher -----------------------------------

extern "C" void kernel_launch(void* const* d_in, const int* in_sizes, int n_in,
                              void* d_out, int out_size, void* d_ws, size_t ws_size,
                              hipStream_t stream) {
    (void)in_sizes; (void)n_in; (void)out_size; (void)ws_size;
    const int*   x     = (const int*)  d_in[0];
    const float* tok   = (const float*)d_in[1];
    const float* pos   = (const float*)d_in[2];
    const float* Wih   = (const float*)d_in[3];
    const float* Whh   = (const float*)d_in[4];
    const float* bih   = (const float*)d_in[5];
    const float* bhh   = (const float*)d_in[6];
    const float* gamma = (const float*)d_in[7];
    const float* beta  = (const float*)d_in[8];

    float* outl = (float*)d_out;                               // [32][128][32000]
    float* outh = outl + (size_t)Bn * Tn * Vn;                 // [32][128][192]

    // small persistent scratch in d_ws (~17 MB)
    char* w = (char*)d_ws;
    f16*   wih16 = (f16*)w;   w += (size_t)Ln * H4n * Dn * 2;  // 1769472
    f16*   whh16 = (f16*)w;   w += (size_t)Ln * H4n * Dn * 2;
    float* bias  = (float*)w; w += (size_t)Ln * H4n * 4;       // 18432
    f16*   emb16 = (f16*)w;   w += (size_t)Vn * Dn * 2;        // 12288000
    f16*   hln   = (f16*)w;   w += (size_t)Tn * Bn * Dn * 2;   // 1572864
    int*   flags = (int*)w;                                    // 2*6*128 ints
    int* hready  = flags;
    int* gxready = flags + Ln * Tn;

    // big dead-before-head intermediates live in d_out's logits region (~49 MB << 524 MB)
    char* scr = (char*)d_out;
    f16* seqb = (f16*)scr;                                     // [7][4096][192] f16
    f16* gxb  = (f16*)(scr + (size_t)7 * Tn * Bn * Dn * 2);    // [6][128][GXT] f16

    k_prep    <<<4096, 256, 0, stream>>>(Wih, Whh, bih, bhh, tok, wih16, whh16, bias, emb16, flags);
    k_embed   <<<1024, 256, 0, stream>>>(x, tok, pos, seqb);
    k_gx0     <<<  32, 768, 0, stream>>>(wih16, bias, seqb, gxb);
    k_pipeline<<<  11, 768, 0, stream>>>(wih16, whh16, bias, seqb, gxb, hready, gxready);
    k_ln      <<<1024, 256, 0, stream>>>(seqb + (size_t)Ln * Tn * Bn * Dn, gamma, beta, outh, hln);
    k_head    <<<8192, 512, 0, stream>>>(hln, emb16, outl);
}